// Round 2
// baseline (961.367 us; speedup 1.0000x reference)
//
#include <hip/hip_runtime.h>
#include <hip/hip_bf16.h>

typedef __attribute__((ext_vector_type(8))) short short8;
typedef __attribute__((ext_vector_type(4))) float f32x4;
typedef __hip_bfloat16 bf16;

#define MFMA16(a,b,c) __builtin_amdgcn_mfma_f32_16x16x32_bf16(a,b,c,0,0,0)

__device__ __forceinline__ void gld_lds16(const void* g, void* l) {
  __builtin_amdgcn_global_load_lds((const __attribute__((address_space(1))) void*)g,
                                   (__attribute__((address_space(3))) void*)l, 16, 0, 0);
}

// B=4, T=1024, C=2048, NH=16, HS=128, NLQ=NLKV=512, DHR=64; scale = 1/sqrt(192)

// ---------------- cast f32 -> bf16 (vectorized x4) ----------------
__global__ __launch_bounds__(256) void cast_bf16_kernel(const float* __restrict__ in,
                                                        bf16* __restrict__ out, long n4) {
  long i = (long)blockIdx.x * blockDim.x + threadIdx.x;
  if (i >= n4) return;
  float4 v = ((const float4*)in)[i];
  union { bf16 b[4]; uint2 u; } p;
  p.b[0] = __float2bfloat16(v.x);
  p.b[1] = __float2bfloat16(v.y);
  p.b[2] = __float2bfloat16(v.z);
  p.b[3] = __float2bfloat16(v.w);
  ((uint2*)out)[i] = p.u;
}

// ---------------- transpose f32 (R x C) -> bf16 (C x R) ----------------
__global__ void transpose_cast_kernel(const float* __restrict__ in, bf16* __restrict__ out,
                                      int R, int C) {
  __shared__ float t[32][33];
  int c0 = blockIdx.x * 32, r0 = blockIdx.y * 32;
  for (int j = threadIdx.y; j < 32; j += 8)
    t[j][threadIdx.x] = in[(long)(r0 + j) * C + c0 + threadIdx.x];
  __syncthreads();
  for (int j = threadIdx.y; j < 32; j += 8)
    out[(long)(c0 + j) * R + r0 + threadIdx.x] = __float2bfloat16(t[threadIdx.x][j]);
}

// ---------------- rope ----------------
__global__ __launch_bounds__(256) void rope_kernel(const float* __restrict__ in,
                                                   const float* __restrict__ cosT,
                                                   const float* __restrict__ sinT,
                                                   bf16* __restrict__ out, int H, long total) {
  long i = (long)blockIdx.x * blockDim.x + threadIdx.x;
  if (i >= total) return;
  int pair = (int)(i & 31);
  long rest = i >> 5;
  int h = (int)(rest % H);
  long bt = rest / H;
  int t = (int)(bt & 1023);
  long base = (bt * H + h) * 64 + pair * 2;
  float re = in[base], im = in[base + 1];
  float c = cosT[t * 32 + pair], s = sinT[t * 32 + pair];
  out[base] = __float2bfloat16(re * c - im * s);
  out[base + 1] = __float2bfloat16(re * s + im * c);
}

// ---------------- batched NT bf16 GEMM, m97 structure ----------------
// C[m,n] = sum_k A[m,k]*B[n,k]; linear LDS + global_load_lds 16B staging.
template <int OUT_BF16>
__global__ __launch_bounds__(256) void gemm_nt(const bf16* __restrict__ A,
                                               const bf16* __restrict__ B,
                                               void* __restrict__ Cv, int M, int N, int K,
                                               int lda, int ldb, int ldc,
                                               int adiv, int amod, long astr,
                                               int bdiv, int bmod, long bstr, long cstr) {
  __shared__ bf16 As[128 * 32];
  __shared__ bf16 Bs[128 * 32];
  const int tid = threadIdx.x;
  const int lane = tid & 63;
  const int w = tid >> 6;
  const int wr = w >> 1, wc = w & 1;
  const int z = blockIdx.z;
  A += ((long)((z / adiv) % amod)) * astr;
  B += ((long)((z / bdiv) % bmod)) * bstr;
  const int m0 = blockIdx.x * 128, n0 = blockIdx.y * 128;
  const int l16 = lane & 15, lg = lane >> 4;
  const int r0c = tid >> 2, c8 = (tid & 3) * 8;  // staging: chunk=tid(+256) -> row, 8-elem col
  f32x4 acc[4][4] = {};
  for (int k0 = 0; k0 < K; k0 += 32) {
    __syncthreads();
    gld_lds16(A + (long)(m0 + r0c) * lda + k0 + c8, &As[tid * 8]);
    gld_lds16(A + (long)(m0 + 64 + r0c) * lda + k0 + c8, &As[2048 + tid * 8]);
    gld_lds16(B + (long)(n0 + r0c) * ldb + k0 + c8, &Bs[tid * 8]);
    gld_lds16(B + (long)(n0 + 64 + r0c) * ldb + k0 + c8, &Bs[2048 + tid * 8]);
    __syncthreads();
    short8 af[4], bfr[4];
#pragma unroll
    for (int i = 0; i < 4; ++i) {
      af[i] = *(const short8*)(&As[(wr * 64 + i * 16 + l16) * 32 + lg * 8]);
      bfr[i] = *(const short8*)(&Bs[(wc * 64 + i * 16 + l16) * 32 + lg * 8]);
    }
#pragma unroll
    for (int i = 0; i < 4; ++i)
#pragma unroll
      for (int j2 = 0; j2 < 4; ++j2) acc[i][j2] = MFMA16(af[i], bfr[j2], acc[i][j2]);
  }
#pragma unroll
  for (int i = 0; i < 4; ++i)
#pragma unroll
    for (int j2 = 0; j2 < 4; ++j2) {
      int col = n0 + wc * 64 + j2 * 16 + l16;
      if (col >= N) continue;
      long rbase = (long)(m0 + wr * 64 + i * 16 + lg * 4);
      for (int r = 0; r < 4; ++r) {
        float v = acc[i][j2][r];
        long idx = (long)z * cstr + (rbase + r) * ldc + col;
        if (OUT_BF16) ((bf16*)Cv)[idx] = __float2bfloat16(v);
        else ((float*)Cv)[idx] = v;
      }
    }
}

// ---------------- flash attention ----------------
// grid (16,16,4), 4 waves; wave owns 16 Q rows. K-tile 32x576 staged via
// global_load_lds into LINEAR LDS with pre-swizzled source (chunk ^= row&7);
// reads apply the same XOR -> conflict-free ds_read_b128. V read from global (L2).
__global__ __launch_bounds__(256, 3) void attn_kernel(const bf16* __restrict__ q_c,  // (B,NH,T,512)
                                                      const bf16* __restrict__ q_r,  // (B,T,NH,64)
                                                      const bf16* __restrict__ kc,   // (B,T,512)
                                                      const bf16* __restrict__ kr,   // (B,T,64)
                                                      const bf16* __restrict__ vT,   // (B,NH,128,T)
                                                      float* __restrict__ out) {     // (B,T,2048)
  const int qb = gridDim.x - 1 - blockIdx.x;  // longest blocks dispatch first
  const int h = blockIdx.y, b = blockIdx.z;
  const int t0 = qb * 64;
  const int tid = threadIdx.x, lane = tid & 63, w = tid >> 6;
  const int l16 = lane & 15, lg = lane >> 4;
  __shared__ bf16 Klds[32 * 576];
  __shared__ bf16 Plds[4][16][40];

  short8 aq[18];
  {
    const int trow = t0 + w * 16 + l16;
    const bf16* qcp = q_c + ((long)(b * 16 + h) * 1024 + trow) * 512;
#pragma unroll
    for (int kk = 0; kk < 16; ++kk) aq[kk] = *(const short8*)(qcp + kk * 32 + lg * 8);
    const bf16* qrp = q_r + (((long)b * 1024 + trow) * 16 + h) * 64;
    aq[16] = *(const short8*)(qrp + lg * 8);
    aq[17] = *(const short8*)(qrp + 32 + lg * 8);
  }
  f32x4 oacc[8] = {};
  float m_run[4], l_run[4];
#pragma unroll
  for (int r = 0; r < 4; ++r) { m_run[r] = -1e30f; l_run[r] = 0.f; }
  const int nkb = (t0 + 64) >> 5;
  const float sc = 0.0721687836f * 1.44269504f;  // (1/sqrt(192)) * log2(e)
  const bf16* vbase = vT + (long)(b * 16 + h) * 131072;
  const int rowmin = t0 + w * 16;
  const int swz = l16 & 7;

  for (int kb = 0; kb < nkb; ++kb) {
    const int s0 = kb * 32;
    __syncthreads();  // previous tile's reads done
#pragma unroll
    for (int j = 0; j < 9; ++j) {  // 32 rows x 72 16B-chunks = 2304
      int chunk = tid + 256 * j;
      int row = chunk / 72, c = chunk % 72;
      int cs = c ^ (row & 7);  // pre-swizzled source, linear LDS dest
      const bf16* src = (cs < 64)
          ? kc + ((long)(b * 1024 + s0 + row)) * 512 + cs * 8
          : kr + ((long)(b * 1024 + s0 + row)) * 64 + (cs - 64) * 8;
      gld_lds16(src, &Klds[chunk * 8]);
    }
    __syncthreads();  // vmcnt(0) drained by barrier
    if (s0 >= rowmin + 16) continue;  // wave-uniform: this wave's rows see no such keys

    f32x4 s_acc[2] = {};
#pragma unroll
    for (int kk = 0; kk < 18; ++kk) {
      int u = kk * 4 + lg;
      short8 b0 = *(const short8*)(&Klds[l16 * 576 + ((u ^ swz) * 8)]);
      short8 b1 = *(const short8*)(&Klds[(16 + l16) * 576 + ((u ^ swz) * 8)]);
      s_acc[0] = MFMA16(aq[kk], b0, s_acc[0]);
      s_acc[1] = MFMA16(aq[kk], b1, s_acc[1]);
    }
    const bool need_mask = (s0 + 31 > rowmin);
    float p[2][4], rmax[4];
#pragma unroll
    for (int r = 0; r < 4; ++r) {
      float s0v = s_acc[0][r] * sc, s1v = s_acc[1][r] * sc;
      if (need_mask) {
        int tg = rowmin + lg * 4 + r;
        if (s0 + l16 > tg) s0v = -1e30f;
        if (s0 + 16 + l16 > tg) s1v = -1e30f;
      }
      p[0][r] = s0v; p[1][r] = s1v;
      float mx = fmaxf(s0v, s1v);
      mx = fmaxf(mx, __shfl_xor(mx, 1));
      mx = fmaxf(mx, __shfl_xor(mx, 2));
      mx = fmaxf(mx, __shfl_xor(mx, 4));
      mx = fmaxf(mx, __shfl_xor(mx, 8));
      rmax[r] = mx;
    }
    float alpha[4];
#pragma unroll
    for (int r = 0; r < 4; ++r) {
      float mnew = fmaxf(m_run[r], rmax[r]);
      alpha[r] = exp2f(m_run[r] - mnew);
      m_run[r] = mnew;
      float p0 = exp2f(p[0][r] - mnew);
      float p1 = exp2f(p[1][r] - mnew);
      p[0][r] = p0; p[1][r] = p1;
      float rs = p0 + p1;
      rs += __shfl_xor(rs, 1);
      rs += __shfl_xor(rs, 2);
      rs += __shfl_xor(rs, 4);
      rs += __shfl_xor(rs, 8);
      l_run[r] = l_run[r] * alpha[r] + rs;
    }
#pragma unroll
    for (int f = 0; f < 8; ++f)
#pragma unroll
      for (int r = 0; r < 4; ++r) oacc[f][r] *= alpha[r];
#pragma unroll
    for (int nf = 0; nf < 2; ++nf)
#pragma unroll
      for (int r = 0; r < 4; ++r)
        Plds[w][lg * 4 + r][nf * 16 + l16] = __float2bfloat16(p[nf][r]);
    // same-wave DS write->read, in-order
    short8 pa = *(const short8*)(&Plds[w][l16][lg * 8]);
#pragma unroll
    for (int fb = 0; fb < 2; ++fb) {
      short8 vb[4];
#pragma unroll
      for (int f = 0; f < 4; ++f)
        vb[f] = *(const short8*)(vbase + (long)((fb * 4 + f) * 16 + l16) * 1024 + s0 + lg * 8);
#pragma unroll
      for (int f = 0; f < 4; ++f) oacc[fb * 4 + f] = MFMA16(pa, vb[f], oacc[fb * 4 + f]);
    }
  }
#pragma unroll
  for (int f = 0; f < 8; ++f)
    for (int r = 0; r < 4; ++r) {
      int t = t0 + w * 16 + lg * 4 + r;
      int col = f * 16 + l16;
      out[((long)(b * 1024 + t)) * 2048 + h * 128 + col] = oacc[f][r] / l_run[r];
    }
}

extern "C" void kernel_launch(void* const* d_in, const int* in_sizes, int n_in, void* d_out,
                              int out_size, void* d_ws, size_t ws_size, hipStream_t stream) {
  const float* x = (const float*)d_in[0];
  const float* W_dq = (const float*)d_in[1];
  const float* W_uq = (const float*)d_in[2];
  const float* W_dkv = (const float*)d_in[3];
  const float* W_uk = (const float*)d_in[4];
  const float* W_uv = (const float*)d_in[5];
  const float* W_o = (const float*)d_in[6];
  const float* W_qr = (const float*)d_in[7];
  const float* W_kr = (const float*)d_in[8];
  const float* fcos = (const float*)d_in[9];
  const float* fsin = (const float*)d_in[10];
  float* out = (float*)d_out;

  char* p = (char*)d_ws;
  auto alloc = [&](long bytes) { void* r = p; p += (bytes + 255) & ~255L; return r; };
  bf16* xb = (bf16*)alloc(8388608L * 2);
  bf16* Wdq_b = (bf16*)alloc(1048576L * 2);
  bf16* Wdkv_b = (bf16*)alloc(1048576L * 2);
  bf16* Wkr_b = (bf16*)alloc(131072L * 2);
  bf16* Wqr_b = (bf16*)alloc(524288L * 2);
  bf16* Wo_b = (bf16*)alloc(4194304L * 2);
  bf16* Wuq_b = (bf16*)alloc(1048576L * 2);
  bf16* WukT_b = (bf16*)alloc(1048576L * 2);
  bf16* WuvT_b = (bf16*)alloc(1048576L * 2);
  bf16* c_q_b = (bf16*)alloc(2097152L * 2);
  bf16* c_kv_b = (bf16*)alloc(2097152L * 2);
  bf16* kefT_b = (bf16*)alloc(4194304L * 2);
  bf16* veffT_b = (bf16*)alloc(1048576L * 2);
  bf16* q_c = (bf16*)alloc(33554432L * 2);
  float* c_qr_f = (float*)alloc(4194304L * 4);
  bf16* q_r_b = (bf16*)alloc(4194304L * 2);
  float* c_kr_f = (float*)alloc(262144L * 4);
  bf16* k_r_b = (bf16*)alloc(262144L * 2);
  bf16* vT_b = (bf16*)alloc(8388608L * 2);

  cast_bf16_kernel<<<8192, 256, 0, stream>>>(x, xb, 2097152);
  cast_bf16_kernel<<<1024, 256, 0, stream>>>(W_dq, Wdq_b, 262144);
  cast_bf16_kernel<<<1024, 256, 0, stream>>>(W_dkv, Wdkv_b, 262144);
  cast_bf16_kernel<<<128, 256, 0, stream>>>(W_kr, Wkr_b, 32768);
  cast_bf16_kernel<<<512, 256, 0, stream>>>(W_qr, Wqr_b, 131072);
  cast_bf16_kernel<<<4096, 256, 0, stream>>>(W_o, Wo_b, 1048576);
  cast_bf16_kernel<<<1024, 256, 0, stream>>>(W_uq, Wuq_b, 262144);
  transpose_cast_kernel<<<dim3(16, 64), dim3(32, 8), 0, stream>>>(W_uk, WukT_b, 2048, 512);
  transpose_cast_kernel<<<dim3(16, 64), dim3(32, 8), 0, stream>>>(W_uv, WuvT_b, 2048, 512);

  gemm_nt<1><<<dim3(32, 4, 1), 256, 0, stream>>>(xb, Wdq_b, c_q_b, 4096, 512, 2048, 2048, 2048,
                                                 512, 1, 1, 0, 1, 1, 0, 0);
  gemm_nt<1><<<dim3(32, 4, 1), 256, 0, stream>>>(xb, Wdkv_b, c_kv_b, 4096, 512, 2048, 2048, 2048,
                                                 512, 1, 1, 0, 1, 1, 0, 0);
  gemm_nt<0><<<dim3(32, 1, 1), 256, 0, stream>>>(xb, Wkr_b, c_kr_f, 4096, 64, 2048, 2048, 2048,
                                                 64, 1, 1, 0, 1, 1, 0, 0);
  gemm_nt<1><<<dim3(4, 4, 16), 256, 0, stream>>>(WukT_b, Wuq_b, kefT_b, 512, 512, 128, 2048, 2048,
                                                 512, 1, 16, 128, 1, 16, 128, 262144);
  gemm_nt<1><<<dim3(16, 4, 1), 256, 0, stream>>>(Wo_b, WuvT_b, veffT_b, 2048, 512, 2048, 2048,
                                                 2048, 512, 1, 1, 0, 1, 1, 0, 0);
  gemm_nt<0><<<dim3(32, 8, 1), 256, 0, stream>>>(c_q_b, Wqr_b, c_qr_f, 4096, 1024, 512, 512, 512,
                                                 1024, 1, 1, 0, 1, 1, 0, 0);
  gemm_nt<1><<<dim3(8, 4, 64), 256, 0, stream>>>(c_q_b, kefT_b, q_c, 1024, 512, 512, 512, 512,
                                                 512, 16, 4, 524288, 1, 16, 262144, 524288);
  gemm_nt<1><<<dim3(1, 8, 64), 256, 0, stream>>>(veffT_b, c_kv_b, vT_b, 128, 1024, 512, 512, 512,
                                                 1024, 1, 16, 65536, 16, 4, 524288, 131072);
  rope_kernel<<<8192, 256, 0, stream>>>(c_qr_f, fcos, fsin, q_r_b, 16, 2097152);
  rope_kernel<<<512, 256, 0, stream>>>(c_kr_f, fcos, fsin, k_r_b, 1, 131072);
  attn_kernel<<<dim3(16, 16, 4), 256, 0, stream>>>(q_c, q_r_b, c_kv_b, k_r_b, vT_b, out);
}

// Round 3
// 540.630 us; speedup vs baseline: 1.7782x; 1.7782x over previous
//
#include <hip/hip_runtime.h>
#include <hip/hip_bf16.h>

typedef __attribute__((ext_vector_type(8))) short short8;
typedef __attribute__((ext_vector_type(4))) float f32x4;
typedef __hip_bfloat16 bf16;

#define MFMA16(a,b,c) __builtin_amdgcn_mfma_f32_16x16x32_bf16(a,b,c,0,0,0)

__device__ __forceinline__ void gld_lds16(const void* g, void* l) {
  __builtin_amdgcn_global_load_lds((const __attribute__((address_space(1))) void*)g,
                                   (__attribute__((address_space(3))) void*)l, 16, 0, 0);
}

// B=4, T=1024, C=2048, NH=16, HS=128, NLQ=NLKV=512, DHR=64; scale = 1/sqrt(192)

// ---------------- cast f32 -> bf16 (vectorized x4) ----------------
__global__ __launch_bounds__(256) void cast_bf16_kernel(const float* __restrict__ in,
                                                        bf16* __restrict__ out, long n4) {
  long i = (long)blockIdx.x * blockDim.x + threadIdx.x;
  if (i >= n4) return;
  float4 v = ((const float4*)in)[i];
  union { bf16 b[4]; uint2 u; } p;
  p.b[0] = __float2bfloat16(v.x);
  p.b[1] = __float2bfloat16(v.y);
  p.b[2] = __float2bfloat16(v.z);
  p.b[3] = __float2bfloat16(v.w);
  ((uint2*)out)[i] = p.u;
}

// ---------------- transpose f32 (R x C) -> bf16 (C x R) ----------------
__global__ void transpose_cast_kernel(const float* __restrict__ in, bf16* __restrict__ out,
                                      int R, int C) {
  __shared__ float t[32][33];
  int c0 = blockIdx.x * 32, r0 = blockIdx.y * 32;
  for (int j = threadIdx.y; j < 32; j += 8)
    t[j][threadIdx.x] = in[(long)(r0 + j) * C + c0 + threadIdx.x];
  __syncthreads();
  for (int j = threadIdx.y; j < 32; j += 8)
    out[(long)(c0 + j) * R + r0 + threadIdx.x] = __float2bfloat16(t[threadIdx.x][j]);
}

// ---------------- rope ----------------
__global__ __launch_bounds__(256) void rope_kernel(const float* __restrict__ in,
                                                   const float* __restrict__ cosT,
                                                   const float* __restrict__ sinT,
                                                   bf16* __restrict__ out, int H, long total) {
  long i = (long)blockIdx.x * blockDim.x + threadIdx.x;
  if (i >= total) return;
  int pair = (int)(i & 31);
  long rest = i >> 5;
  int h = (int)(rest % H);
  long bt = rest / H;
  int t = (int)(bt & 1023);
  long base = (bt * H + h) * 64 + pair * 2;
  float re = in[base], im = in[base + 1];
  float c = cosT[t * 32 + pair], s = sinT[t * 32 + pair];
  out[base] = __float2bfloat16(re * c - im * s);
  out[base + 1] = __float2bfloat16(re * s + im * c);
}

// ---------------- batched NT bf16 GEMM, m97 structure (unchanged) ----------------
template <int OUT_BF16>
__global__ __launch_bounds__(256) void gemm_nt(const bf16* __restrict__ A,
                                               const bf16* __restrict__ B,
                                               void* __restrict__ Cv, int M, int N, int K,
                                               int lda, int ldb, int ldc,
                                               int adiv, int amod, long astr,
                                               int bdiv, int bmod, long bstr, long cstr) {
  __shared__ bf16 As[128 * 32];
  __shared__ bf16 Bs[128 * 32];
  const int tid = threadIdx.x;
  const int lane = tid & 63;
  const int w = tid >> 6;
  const int wr = w >> 1, wc = w & 1;
  const int z = blockIdx.z;
  A += ((long)((z / adiv) % amod)) * astr;
  B += ((long)((z / bdiv) % bmod)) * bstr;
  const int m0 = blockIdx.x * 128, n0 = blockIdx.y * 128;
  const int l16 = lane & 15, lg = lane >> 4;
  const int r0c = tid >> 2, c8 = (tid & 3) * 8;
  f32x4 acc[4][4] = {};
  for (int k0 = 0; k0 < K; k0 += 32) {
    __syncthreads();
    gld_lds16(A + (long)(m0 + r0c) * lda + k0 + c8, &As[tid * 8]);
    gld_lds16(A + (long)(m0 + 64 + r0c) * lda + k0 + c8, &As[2048 + tid * 8]);
    gld_lds16(B + (long)(n0 + r0c) * ldb + k0 + c8, &Bs[tid * 8]);
    gld_lds16(B + (long)(n0 + 64 + r0c) * ldb + k0 + c8, &Bs[2048 + tid * 8]);
    __syncthreads();
    short8 af[4], bfr[4];
#pragma unroll
    for (int i = 0; i < 4; ++i) {
      af[i] = *(const short8*)(&As[(wr * 64 + i * 16 + l16) * 32 + lg * 8]);
      bfr[i] = *(const short8*)(&Bs[(wc * 64 + i * 16 + l16) * 32 + lg * 8]);
    }
#pragma unroll
    for (int i = 0; i < 4; ++i)
#pragma unroll
      for (int j2 = 0; j2 < 4; ++j2) acc[i][j2] = MFMA16(af[i], bfr[j2], acc[i][j2]);
  }
#pragma unroll
  for (int i = 0; i < 4; ++i)
#pragma unroll
    for (int j2 = 0; j2 < 4; ++j2) {
      int col = n0 + wc * 64 + j2 * 16 + l16;
      if (col >= N) continue;
      long rbase = (long)(m0 + wr * 64 + i * 16 + lg * 4);
      for (int r = 0; r < 4; ++r) {
        float v = acc[i][j2][r];
        long idx = (long)z * cstr + (rbase + r) * ldc + col;
        if (OUT_BF16) ((bf16*)Cv)[idx] = __float2bfloat16(v);
        else ((float*)Cv)[idx] = v;
      }
    }
}

// ---------------- flash attention, 8-wave, paired q-blocks, 2-phase dbuf ----------------
// grid (4,16,4), block 512. Block handles q-blocks {7-x, x} (constant 36 tiles).
// K tile 32x576 and V tile 128x32 staged via global_load_lds, pre-swizzled source,
// conflict-free swizzled ds_read_b128. Double-buffered; STAGE(t+1) overlaps compute(t).
__global__ __launch_bounds__(512, 2) void attn_kernel(const bf16* __restrict__ q_c,  // (B,NH,T,512)
                                                      const bf16* __restrict__ q_r,  // (B,T,NH,64)
                                                      const bf16* __restrict__ kc,   // (B,T,512)
                                                      const bf16* __restrict__ kr,   // (B,T,64)
                                                      const bf16* __restrict__ vT,   // (B,NH,128,T)
                                                      float* __restrict__ out) {     // (B,T,2048)
  const int x = blockIdx.x, h = blockIdx.y, b = blockIdx.z;
  const int tid = threadIdx.x, lane = tid & 63, w = tid >> 6;
  const int l16 = lane & 15, lg = lane >> 4;
  __shared__ bf16 Klds[2][32 * 576];
  __shared__ bf16 Vlds[2][512 * 8];
  __shared__ bf16 Plds[8][16][40];

  const float sc = 0.0721687836f * 1.44269504f;  // (1/sqrt(192)) * log2(e)
  const bf16* vbase = vT + (long)(b * 16 + h) * 131072;
  const int swz = l16 & 7;
  const int vswz = (l16 >> 1) & 3;

  // tile-invariant staging geometry
  int krow[5], kcs[5];
#pragma unroll
  for (int j = 0; j < 5; ++j) {
    int chunk = tid + 512 * j;
    if (chunk < 2304) {
      int row = chunk / 72, c = chunk % 72;
      krow[j] = row;
      kcs[j] = c ^ (row & 7);
    } else { krow[j] = 0; kcs[j] = 0; }
  }
  const int vd = tid >> 2, vch = (tid & 3) ^ ((tid >> 3) & 3);

  for (int half = 0; half < 2; ++half) {
    const int q = half ? x : (7 - x);
    const int t0 = q * 128;
    const int rowmin = t0 + w * 16;
    const int nt = (t0 + 128) >> 5;

    // load Q fragments (rows t0 + w*16 .. +16)
    short8 aq[18];
    {
      const int trow = t0 + w * 16 + l16;
      const bf16* qcp = q_c + ((long)(b * 16 + h) * 1024 + trow) * 512;
#pragma unroll
      for (int kk = 0; kk < 16; ++kk) aq[kk] = *(const short8*)(qcp + kk * 32 + lg * 8);
      const bf16* qrp = q_r + (((long)b * 1024 + trow) * 16 + h) * 64;
      aq[16] = *(const short8*)(qrp + lg * 8);
      aq[17] = *(const short8*)(qrp + 32 + lg * 8);
    }

    f32x4 oacc[8] = {};
    float m_run[4], l_run[4];
#pragma unroll
    for (int r = 0; r < 4; ++r) { m_run[r] = -1e30f; l_run[r] = 0.f; }

    // staging source pointers for tile 0 (pre-swizzled)
    const bf16* ksrc[5];
    int kstep[5];
#pragma unroll
    for (int j = 0; j < 5; ++j) {
      if (kcs[j] < 64) { ksrc[j] = kc + ((long)b * 1024 + krow[j]) * 512 + kcs[j] * 8; kstep[j] = 32 * 512; }
      else             { ksrc[j] = kr + ((long)b * 1024 + krow[j]) * 64 + (kcs[j] - 64) * 8; kstep[j] = 32 * 64; }
    }
    const bf16* vsrc = vbase + (long)vd * 1024 + vch * 8;

    auto STAGE = [&](int cc) {
#pragma unroll
      for (int j = 0; j < 4; ++j) {
        gld_lds16(ksrc[j], &Klds[cc][(tid + 512 * j) * 8]);
        ksrc[j] += kstep[j];
      }
      if (tid < 256) {
        gld_lds16(ksrc[4], &Klds[cc][(tid + 2048) * 8]);
        ksrc[4] += kstep[4];
      }
      gld_lds16(vsrc, &Vlds[cc][tid * 8]);
      vsrc += 32;
    };

    int cur = 0;
    STAGE(0);
    __syncthreads();

    for (int t = 0; t < nt; ++t) {
      if (t + 1 < nt) STAGE(cur ^ 1);
      const int s0 = t * 32;
      if (s0 < rowmin + 16) {  // wave-uniform causal skip
        const bf16* Kb = &Klds[cur][0];
        f32x4 s_acc[2] = {};
#pragma unroll
        for (int kk = 0; kk < 18; ++kk) {
          int u = kk * 4 + lg;
          short8 b0 = *(const short8*)(Kb + l16 * 576 + ((u ^ swz) * 8));
          short8 b1 = *(const short8*)(Kb + (16 + l16) * 576 + ((u ^ swz) * 8));
          s_acc[0] = MFMA16(aq[kk], b0, s_acc[0]);
          s_acc[1] = MFMA16(aq[kk], b1, s_acc[1]);
        }
        const bool need_mask = (s0 + 31 > rowmin);
        float p[2][4], rmax[4];
#pragma unroll
        for (int r = 0; r < 4; ++r) {
          float s0v = s_acc[0][r] * sc, s1v = s_acc[1][r] * sc;
          if (need_mask) {
            int tg = rowmin + lg * 4 + r;
            if (s0 + l16 > tg) s0v = -1e30f;
            if (s0 + 16 + l16 > tg) s1v = -1e30f;
          }
          p[0][r] = s0v; p[1][r] = s1v;
          float mx = fmaxf(s0v, s1v);
          mx = fmaxf(mx, __shfl_xor(mx, 1));
          mx = fmaxf(mx, __shfl_xor(mx, 2));
          mx = fmaxf(mx, __shfl_xor(mx, 4));
          mx = fmaxf(mx, __shfl_xor(mx, 8));
          rmax[r] = mx;
        }
        // defer-max (T13, THR=8): only rescale when the running max grew enough
        float need = rmax[0] - m_run[0];
        need = fmaxf(need, rmax[1] - m_run[1]);
        need = fmaxf(need, rmax[2] - m_run[2]);
        need = fmaxf(need, rmax[3] - m_run[3]);
        if (__any(need > 8.0f)) {
          float alpha[4];
#pragma unroll
          for (int r = 0; r < 4; ++r) {
            float mnew = fmaxf(m_run[r], rmax[r]);
            alpha[r] = exp2f(m_run[r] - mnew);
            m_run[r] = mnew;
            l_run[r] *= alpha[r];
          }
#pragma unroll
          for (int f = 0; f < 8; ++f)
#pragma unroll
            for (int r = 0; r < 4; ++r) oacc[f][r] *= alpha[r];
        }
#pragma unroll
        for (int r = 0; r < 4; ++r) {
          float p0 = exp2f(p[0][r] - m_run[r]);
          float p1 = exp2f(p[1][r] - m_run[r]);
          p[0][r] = p0; p[1][r] = p1;
          float rs = p0 + p1;
          rs += __shfl_xor(rs, 1);
          rs += __shfl_xor(rs, 2);
          rs += __shfl_xor(rs, 4);
          rs += __shfl_xor(rs, 8);
          l_run[r] += rs;
        }
#pragma unroll
        for (int nf = 0; nf < 2; ++nf)
#pragma unroll
          for (int r = 0; r < 4; ++r)
            Plds[w][lg * 4 + r][nf * 16 + l16] = __float2bfloat16(p[nf][r]);
        // same-wave DS write->read: in-order, compiler inserts lgkmcnt
        short8 pa = *(const short8*)(&Plds[w][l16][lg * 8]);
        const bf16* Vb = &Vlds[cur][0];
#pragma unroll
        for (int f = 0; f < 8; ++f) {
          int slot = (f * 16 + l16) * 4 + (lg ^ vswz);
          short8 vb = *(const short8*)(Vb + slot * 8);
          oacc[f] = MFMA16(pa, vb, oacc[f]);
        }
      }
      __syncthreads();
      cur ^= 1;
    }

#pragma unroll
    for (int f = 0; f < 8; ++f)
#pragma unroll
      for (int r = 0; r < 4; ++r) {
        int t = t0 + w * 16 + lg * 4 + r;
        int col = f * 16 + l16;
        out[((long)(b * 1024 + t)) * 2048 + h * 128 + col] = oacc[f][r] / l_run[r];
      }
  }
}

extern "C" void kernel_launch(void* const* d_in, const int* in_sizes, int n_in, void* d_out,
                              int out_size, void* d_ws, size_t ws_size, hipStream_t stream) {
  const float* x = (const float*)d_in[0];
  const float* W_dq = (const float*)d_in[1];
  const float* W_uq = (const float*)d_in[2];
  const float* W_dkv = (const float*)d_in[3];
  const float* W_uk = (const float*)d_in[4];
  const float* W_uv = (const float*)d_in[5];
  const float* W_o = (const float*)d_in[6];
  const float* W_qr = (const float*)d_in[7];
  const float* W_kr = (const float*)d_in[8];
  const float* fcos = (const float*)d_in[9];
  const float* fsin = (const float*)d_in[10];
  float* out = (float*)d_out;

  char* p = (char*)d_ws;
  auto alloc = [&](long bytes) { void* r = p; p += (bytes + 255) & ~255L; return r; };
  bf16* xb = (bf16*)alloc(8388608L * 2);
  bf16* Wdq_b = (bf16*)alloc(1048576L * 2);
  bf16* Wdkv_b = (bf16*)alloc(1048576L * 2);
  bf16* Wkr_b = (bf16*)alloc(131072L * 2);
  bf16* Wqr_b = (bf16*)alloc(524288L * 2);
  bf16* Wo_b = (bf16*)alloc(4194304L * 2);
  bf16* Wuq_b = (bf16*)alloc(1048576L * 2);
  bf16* WukT_b = (bf16*)alloc(1048576L * 2);
  bf16* WuvT_b = (bf16*)alloc(1048576L * 2);
  bf16* c_q_b = (bf16*)alloc(2097152L * 2);
  bf16* c_kv_b = (bf16*)alloc(2097152L * 2);
  bf16* kefT_b = (bf16*)alloc(4194304L * 2);
  bf16* veffT_b = (bf16*)alloc(1048576L * 2);
  bf16* q_c = (bf16*)alloc(33554432L * 2);
  float* c_qr_f = (float*)alloc(4194304L * 4);
  bf16* q_r_b = (bf16*)alloc(4194304L * 2);
  float* c_kr_f = (float*)alloc(262144L * 4);
  bf16* k_r_b = (bf16*)alloc(262144L * 2);
  bf16* vT_b = (bf16*)alloc(8388608L * 2);

  cast_bf16_kernel<<<8192, 256, 0, stream>>>(x, xb, 2097152);
  cast_bf16_kernel<<<1024, 256, 0, stream>>>(W_dq, Wdq_b, 262144);
  cast_bf16_kernel<<<1024, 256, 0, stream>>>(W_dkv, Wdkv_b, 262144);
  cast_bf16_kernel<<<128, 256, 0, stream>>>(W_kr, Wkr_b, 32768);
  cast_bf16_kernel<<<512, 256, 0, stream>>>(W_qr, Wqr_b, 131072);
  cast_bf16_kernel<<<4096, 256, 0, stream>>>(W_o, Wo_b, 1048576);
  cast_bf16_kernel<<<1024, 256, 0, stream>>>(W_uq, Wuq_b, 262144);
  transpose_cast_kernel<<<dim3(16, 64), dim3(32, 8), 0, stream>>>(W_uk, WukT_b, 2048, 512);
  transpose_cast_kernel<<<dim3(16, 64), dim3(32, 8), 0, stream>>>(W_uv, WuvT_b, 2048, 512);

  gemm_nt<1><<<dim3(32, 4, 1), 256, 0, stream>>>(xb, Wdq_b, c_q_b, 4096, 512, 2048, 2048, 2048,
                                                 512, 1, 1, 0, 1, 1, 0, 0);
  gemm_nt<1><<<dim3(32, 4, 1), 256, 0, stream>>>(xb, Wdkv_b, c_kv_b, 4096, 512, 2048, 2048, 2048,
                                                 512, 1, 1, 0, 1, 1, 0, 0);
  gemm_nt<0><<<dim3(32, 1, 1), 256, 0, stream>>>(xb, Wkr_b, c_kr_f, 4096, 64, 2048, 2048, 2048,
                                                 64, 1, 1, 0, 1, 1, 0, 0);
  gemm_nt<1><<<dim3(4, 4, 16), 256, 0, stream>>>(WukT_b, Wuq_b, kefT_b, 512, 512, 128, 2048, 2048,
                                                 512, 1, 16, 128, 1, 16, 128, 262144);
  gemm_nt<1><<<dim3(16, 4, 1), 256, 0, stream>>>(Wo_b, WuvT_b, veffT_b, 2048, 512, 2048, 2048,
                                                 2048, 512, 1, 1, 0, 1, 1, 0, 0);
  gemm_nt<0><<<dim3(32, 8, 1), 256, 0, stream>>>(c_q_b, Wqr_b, c_qr_f, 4096, 1024, 512, 512, 512,
                                                 1024, 1, 1, 0, 1, 1, 0, 0);
  gemm_nt<1><<<dim3(8, 4, 64), 256, 0, stream>>>(c_q_b, kefT_b, q_c, 1024, 512, 512, 512, 512,
                                                 512, 16, 4, 524288, 1, 16, 262144, 524288);
  gemm_nt<1><<<dim3(1, 8, 64), 256, 0, stream>>>(veffT_b, c_kv_b, vT_b, 128, 1024, 512, 512, 512,
                                                 1024, 1, 16, 65536, 16, 4, 524288, 131072);
  rope_kernel<<<8192, 256, 0, stream>>>(c_qr_f, fcos, fsin, q_r_b, 16, 2097152);
  rope_kernel<<<512, 256, 0, stream>>>(c_kr_f, fcos, fsin, k_r_b, 1, 131072);
  attn_kernel<<<dim3(4, 16, 4), 512, 0, stream>>>(q_c, q_r_b, c_kv_b, k_r_b, vT_b, out);
}

// Round 4
// 529.993 us; speedup vs baseline: 1.8139x; 1.0201x over previous
//
#include <hip/hip_runtime.h>
#include <hip/hip_bf16.h>

typedef __attribute__((ext_vector_type(8))) short short8;
typedef __attribute__((ext_vector_type(4))) float f32x4;
typedef __hip_bfloat16 bf16;

#define MFMA16(a,b,c) __builtin_amdgcn_mfma_f32_16x16x32_bf16(a,b,c,0,0,0)

__device__ __forceinline__ void gld_lds16(const void* g, void* l) {
  __builtin_amdgcn_global_load_lds((const __attribute__((address_space(1))) void*)g,
                                   (__attribute__((address_space(3))) void*)l, 16, 0, 0);
}

// B=4, T=1024, C=2048, NH=16, HS=128, NLQ=NLKV=512, DHR=64; scale = 1/sqrt(192)

// ---------------- cast f32 -> bf16 (vectorized x4) ----------------
__global__ __launch_bounds__(256) void cast_bf16_kernel(const float* __restrict__ in,
                                                        bf16* __restrict__ out, long n4) {
  long i = (long)blockIdx.x * blockDim.x + threadIdx.x;
  if (i >= n4) return;
  float4 v = ((const float4*)in)[i];
  union { bf16 b[4]; uint2 u; } p;
  p.b[0] = __float2bfloat16(v.x);
  p.b[1] = __float2bfloat16(v.y);
  p.b[2] = __float2bfloat16(v.z);
  p.b[3] = __float2bfloat16(v.w);
  ((uint2*)out)[i] = p.u;
}

// ---------------- transpose f32 (R x C) -> bf16 (C x R) ----------------
__global__ void transpose_cast_kernel(const float* __restrict__ in, bf16* __restrict__ out,
                                      int R, int C) {
  __shared__ float t[32][33];
  int c0 = blockIdx.x * 32, r0 = blockIdx.y * 32;
  for (int j = threadIdx.y; j < 32; j += 8)
    t[j][threadIdx.x] = in[(long)(r0 + j) * C + c0 + threadIdx.x];
  __syncthreads();
  for (int j = threadIdx.y; j < 32; j += 8)
    out[(long)(c0 + j) * R + r0 + threadIdx.x] = __float2bfloat16(t[threadIdx.x][j]);
}

// ---------------- rope for q_r: f32 (BT,16,64) -> bf16 same layout ----------------
__global__ __launch_bounds__(256) void rope_q_kernel(const float* __restrict__ in,
                                                     const float* __restrict__ cosT,
                                                     const float* __restrict__ sinT,
                                                     bf16* __restrict__ out, long total) {
  long i = (long)blockIdx.x * blockDim.x + threadIdx.x;
  if (i >= total) return;
  int pair = (int)(i & 31);
  long rest = i >> 5;
  int h = (int)(rest & 15);
  long bt = rest >> 4;
  int t = (int)(bt & 1023);
  long base = (bt * 16 + h) * 64 + pair * 2;
  float re = in[base], im = in[base + 1];
  float c = cosT[t * 32 + pair], s = sinT[t * 32 + pair];
  out[base] = __float2bfloat16(re * c - im * s);
  out[base + 1] = __float2bfloat16(re * s + im * c);
}

// ---------------- rope for k_r: bf16 strided (ckv_all cols 1024..1087) -> (B,T,64) ----------------
__global__ __launch_bounds__(256) void rope_k_kernel(const bf16* __restrict__ ckv_all,
                                                     const float* __restrict__ cosT,
                                                     const float* __restrict__ sinT,
                                                     bf16* __restrict__ out, long total) {
  long i = (long)blockIdx.x * blockDim.x + threadIdx.x;
  if (i >= total) return;
  int pair = (int)(i & 31);
  long bt = i >> 5;
  int t = (int)(bt & 1023);
  const bf16* src = ckv_all + bt * 1088 + 1024 + pair * 2;
  float re = __bfloat162float(src[0]), im = __bfloat162float(src[1]);
  float c = cosT[t * 32 + pair], s = sinT[t * 32 + pair];
  out[bt * 64 + pair * 2] = __float2bfloat16(re * c - im * s);
  out[bt * 64 + pair * 2 + 1] = __float2bfloat16(re * s + im * c);
}

// ---------------- batched NT bf16 GEMM, m97 structure ----------------
// OUT: 0 = f32 store, 1 = bf16 store, 2 = f32 atomicAdd (split-K)
template <int OUT>
__global__ __launch_bounds__(256) void gemm_nt(const bf16* __restrict__ A,
                                               const bf16* __restrict__ B,
                                               void* __restrict__ Cv, int M, int N, int K,
                                               int lda, int ldb, int ldc,
                                               int adiv, int amod, long astr,
                                               int bdiv, int bmod, long bstr, long cstr) {
  __shared__ bf16 As[128 * 32];
  __shared__ bf16 Bs[128 * 32];
  const int tid = threadIdx.x;
  const int lane = tid & 63;
  const int w = tid >> 6;
  const int wr = w >> 1, wc = w & 1;
  const int z = blockIdx.z;
  A += ((long)((z / adiv) % amod)) * astr;
  B += ((long)((z / bdiv) % bmod)) * bstr;
  const int m0 = blockIdx.x * 128, n0 = blockIdx.y * 128;
  const int l16 = lane & 15, lg = lane >> 4;
  const int r0c = tid >> 2, c8 = (tid & 3) * 8;
  f32x4 acc[4][4] = {};
  for (int k0 = 0; k0 < K; k0 += 32) {
    __syncthreads();
    gld_lds16(A + (long)(m0 + r0c) * lda + k0 + c8, &As[tid * 8]);
    gld_lds16(A + (long)(m0 + 64 + r0c) * lda + k0 + c8, &As[2048 + tid * 8]);
    gld_lds16(B + (long)(n0 + r0c) * ldb + k0 + c8, &Bs[tid * 8]);
    gld_lds16(B + (long)(n0 + 64 + r0c) * ldb + k0 + c8, &Bs[2048 + tid * 8]);
    __syncthreads();
    short8 af[4], bfr[4];
#pragma unroll
    for (int i = 0; i < 4; ++i) {
      af[i] = *(const short8*)(&As[(wr * 64 + i * 16 + l16) * 32 + lg * 8]);
      bfr[i] = *(const short8*)(&Bs[(wc * 64 + i * 16 + l16) * 32 + lg * 8]);
    }
#pragma unroll
    for (int i = 0; i < 4; ++i)
#pragma unroll
      for (int j2 = 0; j2 < 4; ++j2) acc[i][j2] = MFMA16(af[i], bfr[j2], acc[i][j2]);
  }
#pragma unroll
  for (int i = 0; i < 4; ++i)
#pragma unroll
    for (int j2 = 0; j2 < 4; ++j2) {
      int col = n0 + wc * 64 + j2 * 16 + l16;
      if (col >= N) continue;
      long rbase = (long)(m0 + wr * 64 + i * 16 + lg * 4);
      for (int r = 0; r < 4; ++r) {
        float v = acc[i][j2][r];
        long idx = (long)z * cstr + (rbase + r) * ldc + col;
        if (OUT == 1) ((bf16*)Cv)[idx] = __float2bfloat16(v);
        else if (OUT == 0) ((float*)Cv)[idx] = v;
        else atomicAdd(&((float*)Cv)[idx], v);
      }
    }
}

// ---------------- flash attention: per-head q_h/k_h (D_qk=192), 8-wave, dbuf ----------------
// grid (4,16,4), block 512; block does q-blocks {7-x, x} (36 tiles).
// K tile 32x192 (k_h 128 + k_r 64), V tile 128x32; global_load_lds, pre-swizzled src.
__global__ __launch_bounds__(512, 6) void attn_kernel(const bf16* __restrict__ q_h,  // (B,T,NH,128)
                                                      const bf16* __restrict__ q_r,  // (B,T,NH,64)
                                                      const bf16* __restrict__ kh,   // (B,T,NH,128)
                                                      const bf16* __restrict__ kr,   // (B,T,64)
                                                      const bf16* __restrict__ vT,   // (B,NH,128,T)
                                                      float* __restrict__ out) {     // (B,T,2048)
  const int x = blockIdx.x, h = blockIdx.y, b = blockIdx.z;
  const int tid = threadIdx.x, lane = tid & 63, w = tid >> 6;
  const int l16 = lane & 15, lg = lane >> 4;
  __shared__ bf16 Klds[2][32 * 192];
  __shared__ bf16 Vlds[2][512 * 8];
  __shared__ bf16 Plds[8][16][40];

  const float sc = 0.0721687836f * 1.44269504f;  // (1/sqrt(192)) * log2(e)
  const bf16* vbase = vT + (long)(b * 16 + h) * 131072;
  const int swz = l16 & 7;
  const int vswz = (l16 >> 1) & 3;

  // K staging geometry: 768 chunks = 32 rows x 24 (16 from k_h, 8 from k_r)
  int krow[2], kcs[2];
#pragma unroll
  for (int j = 0; j < 2; ++j) {
    int chunk = tid + 512 * j;
    int row = chunk / 24, c = chunk % 24;
    krow[j] = row & 31;
    kcs[j] = c ^ (row & 7);
  }
  const int vd = tid >> 2, vch = (tid & 3) ^ ((tid >> 3) & 3);

  for (int half = 0; half < 2; ++half) {
    const int q = half ? x : (7 - x);
    const int t0 = q * 128;
    const int rowmin = t0 + w * 16;
    const int nt = (t0 + 128) >> 5;

    short8 aq[6];
    {
      const int trow = t0 + w * 16 + l16;
      const bf16* qhp = q_h + ((long)(b * 1024 + trow)) * 2048 + h * 128;
#pragma unroll
      for (int kk = 0; kk < 4; ++kk) aq[kk] = *(const short8*)(qhp + kk * 32 + lg * 8);
      const bf16* qrp = q_r + (((long)b * 1024 + trow) * 16 + h) * 64;
      aq[4] = *(const short8*)(qrp + lg * 8);
      aq[5] = *(const short8*)(qrp + 32 + lg * 8);
    }

    f32x4 oacc[8] = {};
    float m_run[4], l_run[4];
#pragma unroll
    for (int r = 0; r < 4; ++r) { m_run[r] = -1e30f; l_run[r] = 0.f; }

    const bf16* ksrc[2];
    int kstep[2];
#pragma unroll
    for (int j = 0; j < 2; ++j) {
      if (kcs[j] < 16) { ksrc[j] = kh + ((long)b * 1024 + krow[j]) * 2048 + h * 128 + kcs[j] * 8; kstep[j] = 32 * 2048; }
      else             { ksrc[j] = kr + ((long)b * 1024 + krow[j]) * 64 + (kcs[j] - 16) * 8; kstep[j] = 32 * 64; }
    }
    const bf16* vsrc = vbase + (long)vd * 1024 + vch * 8;

    auto STAGE = [&](int cc) {
      gld_lds16(ksrc[0], &Klds[cc][tid * 8]);
      ksrc[0] += kstep[0];
      if (tid < 256) {
        gld_lds16(ksrc[1], &Klds[cc][(tid + 512) * 8]);
        ksrc[1] += kstep[1];
      }
      gld_lds16(vsrc, &Vlds[cc][tid * 8]);
      vsrc += 32;
    };

    int cur = 0;
    STAGE(0);
    __syncthreads();

    for (int t = 0; t < nt; ++t) {
      if (t + 1 < nt) STAGE(cur ^ 1);
      const int s0 = t * 32;
      if (s0 < rowmin + 16) {  // wave-uniform causal skip
        const bf16* Kb = &Klds[cur][0];
        f32x4 s_acc[2] = {};
#pragma unroll
        for (int kk = 0; kk < 6; ++kk) {
          int u = kk * 4 + lg;
          short8 b0 = *(const short8*)(Kb + l16 * 192 + ((u ^ swz) * 8));
          short8 b1 = *(const short8*)(Kb + (16 + l16) * 192 + ((u ^ swz) * 8));
          s_acc[0] = MFMA16(aq[kk], b0, s_acc[0]);
          s_acc[1] = MFMA16(aq[kk], b1, s_acc[1]);
        }
        const bool need_mask = (s0 + 31 > rowmin);
        float p[2][4], rmax[4];
#pragma unroll
        for (int r = 0; r < 4; ++r) {
          float s0v = s_acc[0][r] * sc, s1v = s_acc[1][r] * sc;
          if (need_mask) {
            int tg = rowmin + lg * 4 + r;
            if (s0 + l16 > tg) s0v = -1e30f;
            if (s0 + 16 + l16 > tg) s1v = -1e30f;
          }
          p[0][r] = s0v; p[1][r] = s1v;
          float mx = fmaxf(s0v, s1v);
          mx = fmaxf(mx, __shfl_xor(mx, 1));
          mx = fmaxf(mx, __shfl_xor(mx, 2));
          mx = fmaxf(mx, __shfl_xor(mx, 4));
          mx = fmaxf(mx, __shfl_xor(mx, 8));
          rmax[r] = mx;
        }
        float need = rmax[0] - m_run[0];
        need = fmaxf(need, rmax[1] - m_run[1]);
        need = fmaxf(need, rmax[2] - m_run[2]);
        need = fmaxf(need, rmax[3] - m_run[3]);
        if (__any(need > 8.0f)) {
          float alpha[4];
#pragma unroll
          for (int r = 0; r < 4; ++r) {
            float mnew = fmaxf(m_run[r], rmax[r]);
            alpha[r] = exp2f(m_run[r] - mnew);
            m_run[r] = mnew;
            l_run[r] *= alpha[r];
          }
#pragma unroll
          for (int f = 0; f < 8; ++f)
#pragma unroll
            for (int r = 0; r < 4; ++r) oacc[f][r] *= alpha[r];
        }
#pragma unroll
        for (int r = 0; r < 4; ++r) {
          float p0 = exp2f(p[0][r] - m_run[r]);
          float p1 = exp2f(p[1][r] - m_run[r]);
          p[0][r] = p0; p[1][r] = p1;
          float rs = p0 + p1;
          rs += __shfl_xor(rs, 1);
          rs += __shfl_xor(rs, 2);
          rs += __shfl_xor(rs, 4);
          rs += __shfl_xor(rs, 8);
          l_run[r] += rs;
        }
#pragma unroll
        for (int nf = 0; nf < 2; ++nf)
#pragma unroll
          for (int r = 0; r < 4; ++r)
            Plds[w][lg * 4 + r][nf * 16 + l16] = __float2bfloat16(p[nf][r]);
        short8 pa = *(const short8*)(&Plds[w][l16][lg * 8]);
        const bf16* Vb = &Vlds[cur][0];
#pragma unroll
        for (int f = 0; f < 8; ++f) {
          int slot = (f * 16 + l16) * 4 + (lg ^ vswz);
          short8 vb = *(const short8*)(Vb + slot * 8);
          oacc[f] = MFMA16(pa, vb, oacc[f]);
        }
      }
      __syncthreads();
      cur ^= 1;
    }

#pragma unroll
    for (int f = 0; f < 8; ++f)
#pragma unroll
      for (int r = 0; r < 4; ++r) {
        int t = t0 + w * 16 + lg * 4 + r;
        int col = f * 16 + l16;
        out[((long)(b * 1024 + t)) * 2048 + h * 128 + col] = oacc[f][r] / l_run[r];
      }
  }
}

extern "C" void kernel_launch(void* const* d_in, const int* in_sizes, int n_in, void* d_out,
                              int out_size, void* d_ws, size_t ws_size, hipStream_t stream) {
  const float* x = (const float*)d_in[0];
  const float* W_dq = (const float*)d_in[1];
  const float* W_uq = (const float*)d_in[2];
  const float* W_dkv = (const float*)d_in[3];
  const float* W_uk = (const float*)d_in[4];
  const float* W_uv = (const float*)d_in[5];
  const float* W_o = (const float*)d_in[6];
  const float* W_qr = (const float*)d_in[7];
  const float* W_kr = (const float*)d_in[8];
  const float* fcos = (const float*)d_in[9];
  const float* fsin = (const float*)d_in[10];
  float* out = (float*)d_out;

  char* p = (char*)d_ws;
  auto alloc = [&](long bytes) { void* r = p; p += (bytes + 255) & ~255L; return r; };
  bf16* xb = (bf16*)alloc(8388608L * 2);        // (4096,2048)
  bf16* Wcat = (bf16*)alloc(1152L * 2048 * 2);  // rows: Wdq(512)+Wdkv(512)+Wkr(64)+pad(64)
  bf16* Wqr_b = (bf16*)alloc(524288L * 2);      // (1024,512)
  bf16* Wo_b = (bf16*)alloc(4194304L * 2);      // (2048,2048)
  bf16* Wuk_b = (bf16*)alloc(1048576L * 2);     // (2048,512)
  bf16* WuqT_b = (bf16*)alloc(1048576L * 2);    // (2048,512) = W_uq^T
  bf16* WuvT_b = (bf16*)alloc(1048576L * 2);    // (512,2048) = W_uv^T
  bf16* ckv_all = (bf16*)alloc(4096L * 1088 * 2);  // (4096,1088): c_q|c_kv|c_kr
  float* veff_f32 = (float*)alloc(1048576L * 4);   // (2048,512) f32 split-K accum
  bf16* veffT_b = (bf16*)alloc(1048576L * 2);      // (2048,512)
  bf16* q_h = (bf16*)alloc(8388608L * 2);       // (4096,2048) = (B,T,NH,128)
  bf16* k_h = (bf16*)alloc(8388608L * 2);       // (4096,2048) = (B,T,NH,128)
  float* c_qr_f = (float*)alloc(4194304L * 4);  // (4096,1024)
  bf16* q_r_b = (bf16*)alloc(4194304L * 2);     // (B,T,16,64)
  bf16* k_r_b = (bf16*)alloc(262144L * 2);      // (B,T,64)
  bf16* vT_b = (bf16*)alloc(8388608L * 2);      // (B,NH,128,T)

  // casts / transposes
  cast_bf16_kernel<<<8192, 256, 0, stream>>>(x, xb, 2097152);
  cast_bf16_kernel<<<1024, 256, 0, stream>>>(W_dq, Wcat, 262144);
  cast_bf16_kernel<<<1024, 256, 0, stream>>>(W_dkv, Wcat + 512L * 2048, 262144);
  cast_bf16_kernel<<<128, 256, 0, stream>>>(W_kr, Wcat + 1024L * 2048, 32768);
  cast_bf16_kernel<<<512, 256, 0, stream>>>(W_qr, Wqr_b, 131072);
  cast_bf16_kernel<<<4096, 256, 0, stream>>>(W_o, Wo_b, 1048576);
  cast_bf16_kernel<<<1024, 256, 0, stream>>>(W_uk, Wuk_b, 262144);
  transpose_cast_kernel<<<dim3(64, 16), dim3(32, 8), 0, stream>>>(W_uq, WuqT_b, 512, 2048);
  transpose_cast_kernel<<<dim3(16, 64), dim3(32, 8), 0, stream>>>(W_uv, WuvT_b, 2048, 512);
  hipMemsetAsync(veff_f32, 0, 1048576L * 4, stream);

  // fused c_q|c_kv|c_kr = x @ Wcat^T : (4096,1088,2048)
  gemm_nt<1><<<dim3(32, 9, 1), 256, 0, stream>>>(xb, Wcat, ckv_all, 4096, 1088, 2048, 2048, 2048,
                                                 1088, 1, 1, 0, 1, 1, 0, 0);
  // veffT = W_o @ W_uv (split-K x4, f32 atomic)
  gemm_nt<2><<<dim3(16, 4, 4), 256, 0, stream>>>(Wo_b, WuvT_b, veff_f32, 2048, 512, 512, 2048,
                                                 2048, 512, 1, 4, 512, 1, 4, 512, 0);
  cast_bf16_kernel<<<1024, 256, 0, stream>>>(veff_f32, veffT_b, 262144);
  // q_h = c_q @ WuqT^T : (4096,2048,512)
  gemm_nt<1><<<dim3(32, 16, 1), 256, 0, stream>>>(ckv_all, WuqT_b, q_h, 4096, 2048, 512, 1088,
                                                  512, 2048, 1, 1, 0, 1, 1, 0, 0);
  // k_h = c_kv @ W_uk^T : (4096,2048,512)
  gemm_nt<1><<<dim3(32, 16, 1), 256, 0, stream>>>(ckv_all + 512, Wuk_b, k_h, 4096, 2048, 512,
                                                  1088, 512, 2048, 1, 1, 0, 1, 1, 0, 0);
  // c_qr = c_q @ W_qr^T (f32 out)
  gemm_nt<0><<<dim3(32, 8, 1), 256, 0, stream>>>(ckv_all, Wqr_b, c_qr_f, 4096, 1024, 512, 1088,
                                                 512, 1024, 1, 1, 0, 1, 1, 0, 0);
  // vT[b,h](d,s) = veffT_h @ c_kv[b]^T
  gemm_nt<1><<<dim3(1, 8, 64), 256, 0, stream>>>(veffT_b, ckv_all + 512, vT_b, 128, 1024, 512,
                                                 512, 1088, 1024, 1, 16, 65536, 16, 4,
                                                 1024L * 1088, 131072);
  // rope
  rope_q_kernel<<<8192, 256, 0, stream>>>(c_qr_f, fcos, fsin, q_r_b, 2097152);
  rope_k_kernel<<<512, 256, 0, stream>>>(ckv_all, fcos, fsin, k_r_b, 131072);
  // attention
  attn_kernel<<<dim3(4, 16, 4), 512, 0, stream>>>(q_h, q_r_b, k_h, k_r_b, vT_b, out);
}

// Round 5
// 390.407 us; speedup vs baseline: 2.4625x; 1.3575x over previous
//
#include <hip/hip_runtime.h>
#include <hip/hip_bf16.h>

typedef __attribute__((ext_vector_type(8))) short short8;
typedef __attribute__((ext_vector_type(4))) float f32x4;
typedef __hip_bfloat16 bf16;

#define MFMA16(a,b,c) __builtin_amdgcn_mfma_f32_16x16x32_bf16(a,b,c,0,0,0)

__device__ __forceinline__ void gld_lds16(const void* g, void* l) {
  __builtin_amdgcn_global_load_lds((const __attribute__((address_space(1))) void*)g,
                                   (__attribute__((address_space(3))) void*)l, 16, 0, 0);
}

// B=4, T=1024, C=2048, NH=16, HS=128, NLQ=NLKV=512, DHR=64; scale = 1/sqrt(192)

// ---------------- cast f32 -> bf16 (vectorized x4) ----------------
__global__ __launch_bounds__(256) void cast_bf16_kernel(const float* __restrict__ in,
                                                        bf16* __restrict__ out, long n4) {
  long i = (long)blockIdx.x * blockDim.x + threadIdx.x;
  if (i >= n4) return;
  float4 v = ((const float4*)in)[i];
  union { bf16 b[4]; uint2 u; } p;
  p.b[0] = __float2bfloat16(v.x);
  p.b[1] = __float2bfloat16(v.y);
  p.b[2] = __float2bfloat16(v.z);
  p.b[3] = __float2bfloat16(v.w);
  ((uint2*)out)[i] = p.u;
}

// ---------------- transpose f32 (R x C) -> bf16 (C x R) ----------------
__global__ void transpose_cast_kernel(const float* __restrict__ in, bf16* __restrict__ out,
                                      int R, int C) {
  __shared__ float t[32][33];
  int c0 = blockIdx.x * 32, r0 = blockIdx.y * 32;
  for (int j = threadIdx.y; j < 32; j += 8)
    t[j][threadIdx.x] = in[(long)(r0 + j) * C + c0 + threadIdx.x];
  __syncthreads();
  for (int j = threadIdx.y; j < 32; j += 8)
    out[(long)(c0 + j) * R + r0 + threadIdx.x] = __float2bfloat16(t[threadIdx.x][j]);
}

// ---------------- rope for q_r: f32 (BT,16,64) -> bf16 same layout ----------------
__global__ __launch_bounds__(256) void rope_q_kernel(const float* __restrict__ in,
                                                     const float* __restrict__ cosT,
                                                     const float* __restrict__ sinT,
                                                     bf16* __restrict__ out, long total) {
  long i = (long)blockIdx.x * blockDim.x + threadIdx.x;
  if (i >= total) return;
  int pair = (int)(i & 31);
  long rest = i >> 5;
  int h = (int)(rest & 15);
  long bt = rest >> 4;
  int t = (int)(bt & 1023);
  long base = (bt * 16 + h) * 64 + pair * 2;
  float re = in[base], im = in[base + 1];
  float c = cosT[t * 32 + pair], s = sinT[t * 32 + pair];
  out[base] = __float2bfloat16(re * c - im * s);
  out[base + 1] = __float2bfloat16(re * s + im * c);
}

// ---------------- rope for k_r: bf16 strided (ckv_all cols 1024..1087) -> (B,T,64) ----------------
__global__ __launch_bounds__(256) void rope_k_kernel(const bf16* __restrict__ ckv_all,
                                                     const float* __restrict__ cosT,
                                                     const float* __restrict__ sinT,
                                                     bf16* __restrict__ out, long total) {
  long i = (long)blockIdx.x * blockDim.x + threadIdx.x;
  if (i >= total) return;
  int pair = (int)(i & 31);
  long bt = i >> 5;
  int t = (int)(bt & 1023);
  const bf16* src = ckv_all + bt * 1088 + 1024 + pair * 2;
  float re = __bfloat162float(src[0]), im = __bfloat162float(src[1]);
  float c = cosT[t * 32 + pair], s = sinT[t * 32 + pair];
  out[bt * 64 + pair * 2] = __float2bfloat16(re * c - im * s);
  out[bt * 64 + pair * 2 + 1] = __float2bfloat16(re * s + im * c);
}

// ---------------- batched NT bf16 GEMM, m97 structure ----------------
// OUT: 0 = f32 store, 1 = bf16 store, 2 = f32 atomicAdd (split-K)
template <int OUT>
__global__ __launch_bounds__(256) void gemm_nt(const bf16* __restrict__ A,
                                               const bf16* __restrict__ B,
                                               void* __restrict__ Cv, int M, int N, int K,
                                               int lda, int ldb, int ldc,
                                               int adiv, int amod, long astr,
                                               int bdiv, int bmod, long bstr, long cstr) {
  __shared__ bf16 As[128 * 32];
  __shared__ bf16 Bs[128 * 32];
  const int tid = threadIdx.x;
  const int lane = tid & 63;
  const int w = tid >> 6;
  const int wr = w >> 1, wc = w & 1;
  const int z = blockIdx.z;
  A += ((long)((z / adiv) % amod)) * astr;
  B += ((long)((z / bdiv) % bmod)) * bstr;
  const int m0 = blockIdx.x * 128, n0 = blockIdx.y * 128;
  const int l16 = lane & 15, lg = lane >> 4;
  const int r0c = tid >> 2, c8 = (tid & 3) * 8;
  f32x4 acc[4][4] = {};
  for (int k0 = 0; k0 < K; k0 += 32) {
    __syncthreads();
    gld_lds16(A + (long)(m0 + r0c) * lda + k0 + c8, &As[tid * 8]);
    gld_lds16(A + (long)(m0 + 64 + r0c) * lda + k0 + c8, &As[2048 + tid * 8]);
    gld_lds16(B + (long)(n0 + r0c) * ldb + k0 + c8, &Bs[tid * 8]);
    gld_lds16(B + (long)(n0 + 64 + r0c) * ldb + k0 + c8, &Bs[2048 + tid * 8]);
    __syncthreads();
    short8 af[4], bfr[4];
#pragma unroll
    for (int i = 0; i < 4; ++i) {
      af[i] = *(const short8*)(&As[(wr * 64 + i * 16 + l16) * 32 + lg * 8]);
      bfr[i] = *(const short8*)(&Bs[(wc * 64 + i * 16 + l16) * 32 + lg * 8]);
    }
#pragma unroll
    for (int i = 0; i < 4; ++i)
#pragma unroll
      for (int j2 = 0; j2 < 4; ++j2) acc[i][j2] = MFMA16(af[i], bfr[j2], acc[i][j2]);
  }
#pragma unroll
  for (int i = 0; i < 4; ++i)
#pragma unroll
    for (int j2 = 0; j2 < 4; ++j2) {
      int col = n0 + wc * 64 + j2 * 16 + l16;
      if (col >= N) continue;
      long rbase = (long)(m0 + wr * 64 + i * 16 + lg * 4);
      for (int r = 0; r < 4; ++r) {
        float v = acc[i][j2][r];
        long idx = (long)z * cstr + (rbase + r) * ldc + col;
        if (OUT == 1) ((bf16*)Cv)[idx] = __float2bfloat16(v);
        else if (OUT == 0) ((float*)Cv)[idx] = v;
        else atomicAdd(&((float*)Cv)[idx], v);
      }
    }
}

// ---------------- flash attention: per-head q_h/k_h (D_qk=192), 8-wave, dbuf ----------------
// grid (4,16,4), block 512; block does q-blocks {7-x, x} (36 tiles).
// K tile 32x192 (k_h 128 + k_r 64), V tile 128x32; global_load_lds, pre-swizzled src.
// __launch_bounds__(512,4): VGPR cap 128 — (512,6) capped at 85 and spilled (R4: VGPR=40, 2x slower).
__global__ __launch_bounds__(512, 4) void attn_kernel(const bf16* __restrict__ q_h,  // (B,T,NH,128)
                                                      const bf16* __restrict__ q_r,  // (B,T,NH,64)
                                                      const bf16* __restrict__ kh,   // (B,T,NH,128)
                                                      const bf16* __restrict__ kr,   // (B,T,64)
                                                      const bf16* __restrict__ vT,   // (B,NH,128,T)
                                                      float* __restrict__ out) {     // (B,T,2048)
  const int x = blockIdx.x, h = blockIdx.y, b = blockIdx.z;
  const int tid = threadIdx.x, lane = tid & 63, w = tid >> 6;
  const int l16 = lane & 15, lg = lane >> 4;
  __shared__ bf16 Klds[2][32 * 192];
  __shared__ bf16 Vlds[2][512 * 8];
  __shared__ bf16 Plds[8][16][40];

  const float sc = 0.0721687836f * 1.44269504f;  // (1/sqrt(192)) * log2(e)
  const bf16* vbase = vT + (long)(b * 16 + h) * 131072;
  const int swz = l16 & 7;
  const int vswz = (l16 >> 1) & 3;

  // K staging geometry: 768 chunks = 32 rows x 24 (16 from k_h, 8 from k_r)
  int krow[2], kcs[2];
#pragma unroll
  for (int j = 0; j < 2; ++j) {
    int chunk = tid + 512 * j;
    int row = chunk / 24, c = chunk % 24;
    krow[j] = row & 31;
    kcs[j] = c ^ (row & 7);
  }
  const int vd = tid >> 2, vch = (tid & 3) ^ ((tid >> 3) & 3);

  for (int half = 0; half < 2; ++half) {
    const int q = half ? x : (7 - x);
    const int t0 = q * 128;
    const int rowmin = t0 + w * 16;
    const int nt = (t0 + 128) >> 5;

    short8 aq[6];
    {
      const int trow = t0 + w * 16 + l16;
      const bf16* qhp = q_h + ((long)(b * 1024 + trow)) * 2048 + h * 128;
#pragma unroll
      for (int kk = 0; kk < 4; ++kk) aq[kk] = *(const short8*)(qhp + kk * 32 + lg * 8);
      const bf16* qrp = q_r + (((long)b * 1024 + trow) * 16 + h) * 64;
      aq[4] = *(const short8*)(qrp + lg * 8);
      aq[5] = *(const short8*)(qrp + 32 + lg * 8);
    }

    f32x4 oacc[8] = {};
    float m_run[4], l_run[4];
#pragma unroll
    for (int r = 0; r < 4; ++r) { m_run[r] = -1e30f; l_run[r] = 0.f; }

    const bf16* ksrc[2];
    int kstep[2];
#pragma unroll
    for (int j = 0; j < 2; ++j) {
      if (kcs[j] < 16) { ksrc[j] = kh + ((long)b * 1024 + krow[j]) * 2048 + h * 128 + kcs[j] * 8; kstep[j] = 32 * 2048; }
      else             { ksrc[j] = kr + ((long)b * 1024 + krow[j]) * 64 + (kcs[j] - 16) * 8; kstep[j] = 32 * 64; }
    }
    const bf16* vsrc = vbase + (long)vd * 1024 + vch * 8;

    auto STAGE = [&](int cc) {
      gld_lds16(ksrc[0], &Klds[cc][tid * 8]);
      ksrc[0] += kstep[0];
      if (tid < 256) {
        gld_lds16(ksrc[1], &Klds[cc][(tid + 512) * 8]);
        ksrc[1] += kstep[1];
      }
      gld_lds16(vsrc, &Vlds[cc][tid * 8]);
      vsrc += 32;
    };

    int cur = 0;
    STAGE(0);
    __syncthreads();

    for (int t = 0; t < nt; ++t) {
      if (t + 1 < nt) STAGE(cur ^ 1);
      const int s0 = t * 32;
      if (s0 < rowmin + 16) {  // wave-uniform causal skip
        const bf16* Kb = &Klds[cur][0];
        f32x4 s_acc[2] = {};
#pragma unroll
        for (int kk = 0; kk < 6; ++kk) {
          int u = kk * 4 + lg;
          short8 b0 = *(const short8*)(Kb + l16 * 192 + ((u ^ swz) * 8));
          short8 b1 = *(const short8*)(Kb + (16 + l16) * 192 + ((u ^ swz) * 8));
          s_acc[0] = MFMA16(aq[kk], b0, s_acc[0]);
          s_acc[1] = MFMA16(aq[kk], b1, s_acc[1]);
        }
        const bool need_mask = (s0 + 31 > rowmin);
        float p[2][4], rmax[4];
#pragma unroll
        for (int r = 0; r < 4; ++r) {
          float s0v = s_acc[0][r] * sc, s1v = s_acc[1][r] * sc;
          if (need_mask) {
            int tg = rowmin + lg * 4 + r;
            if (s0 + l16 > tg) s0v = -1e30f;
            if (s0 + 16 + l16 > tg) s1v = -1e30f;
          }
          p[0][r] = s0v; p[1][r] = s1v;
          float mx = fmaxf(s0v, s1v);
          mx = fmaxf(mx, __shfl_xor(mx, 1));
          mx = fmaxf(mx, __shfl_xor(mx, 2));
          mx = fmaxf(mx, __shfl_xor(mx, 4));
          mx = fmaxf(mx, __shfl_xor(mx, 8));
          rmax[r] = mx;
        }
        float need = rmax[0] - m_run[0];
        need = fmaxf(need, rmax[1] - m_run[1]);
        need = fmaxf(need, rmax[2] - m_run[2]);
        need = fmaxf(need, rmax[3] - m_run[3]);
        if (__any(need > 8.0f)) {
          float alpha[4];
#pragma unroll
          for (int r = 0; r < 4; ++r) {
            float mnew = fmaxf(m_run[r], rmax[r]);
            alpha[r] = exp2f(m_run[r] - mnew);
            m_run[r] = mnew;
            l_run[r] *= alpha[r];
          }
#pragma unroll
          for (int f = 0; f < 8; ++f)
#pragma unroll
            for (int r = 0; r < 4; ++r) oacc[f][r] *= alpha[r];
        }
#pragma unroll
        for (int r = 0; r < 4; ++r) {
          float p0 = exp2f(p[0][r] - m_run[r]);
          float p1 = exp2f(p[1][r] - m_run[r]);
          p[0][r] = p0; p[1][r] = p1;
          float rs = p0 + p1;
          rs += __shfl_xor(rs, 1);
          rs += __shfl_xor(rs, 2);
          rs += __shfl_xor(rs, 4);
          rs += __shfl_xor(rs, 8);
          l_run[r] += rs;
        }
#pragma unroll
        for (int nf = 0; nf < 2; ++nf)
#pragma unroll
          for (int r = 0; r < 4; ++r)
            Plds[w][lg * 4 + r][nf * 16 + l16] = __float2bfloat16(p[nf][r]);
        short8 pa = *(const short8*)(&Plds[w][l16][lg * 8]);
        const bf16* Vb = &Vlds[cur][0];
#pragma unroll
        for (int f = 0; f < 8; ++f) {
          int slot = (f * 16 + l16) * 4 + (lg ^ vswz);
          short8 vb = *(const short8*)(Vb + slot * 8);
          oacc[f] = MFMA16(pa, vb, oacc[f]);
        }
      }
      __syncthreads();
      cur ^= 1;
    }

#pragma unroll
    for (int f = 0; f < 8; ++f)
#pragma unroll
      for (int r = 0; r < 4; ++r) {
        int t = t0 + w * 16 + lg * 4 + r;
        int col = f * 16 + l16;
        out[((long)(b * 1024 + t)) * 2048 + h * 128 + col] = oacc[f][r] / l_run[r];
      }
  }
}

extern "C" void kernel_launch(void* const* d_in, const int* in_sizes, int n_in, void* d_out,
                              int out_size, void* d_ws, size_t ws_size, hipStream_t stream) {
  const float* x = (const float*)d_in[0];
  const float* W_dq = (const float*)d_in[1];
  const float* W_uq = (const float*)d_in[2];
  const float* W_dkv = (const float*)d_in[3];
  const float* W_uk = (const float*)d_in[4];
  const float* W_uv = (const float*)d_in[5];
  const float* W_o = (const float*)d_in[6];
  const float* W_qr = (const float*)d_in[7];
  const float* W_kr = (const float*)d_in[8];
  const float* fcos = (const float*)d_in[9];
  const float* fsin = (const float*)d_in[10];
  float* out = (float*)d_out;

  char* p = (char*)d_ws;
  auto alloc = [&](long bytes) { void* r = p; p += (bytes + 255) & ~255L; return r; };
  bf16* xb = (bf16*)alloc(8388608L * 2);        // (4096,2048)
  bf16* Wcat = (bf16*)alloc(1152L * 2048 * 2);  // rows: Wdq(512)+Wdkv(512)+Wkr(64)+pad(64)
  bf16* Wqr_b = (bf16*)alloc(524288L * 2);      // (1024,512)
  bf16* Wo_b = (bf16*)alloc(4194304L * 2);      // (2048,2048)
  bf16* Wcat2 = (bf16*)alloc(2097152L * 2);     // [WuqT (2048,512) ; Wuk (2048,512)]
  bf16* WuvT_b = (bf16*)alloc(1048576L * 2);    // (512,2048) = W_uv^T
  bf16* ckv_all = (bf16*)alloc(4096L * 1088 * 2);  // (4096,1088): c_q|c_kv|c_kr
  float* veff_f32 = (float*)alloc(1048576L * 4);   // (2048,512) f32 split-K accum
  bf16* veffT_b = (bf16*)alloc(1048576L * 2);      // (2048,512)
  bf16* q_h = (bf16*)alloc(8388608L * 2);       // (4096,2048) = (B,T,NH,128)
  bf16* k_h = (bf16*)alloc(8388608L * 2);       // (4096,2048), contiguous after q_h
  float* c_qr_f = (float*)alloc(4194304L * 4);  // (4096,1024)
  bf16* q_r_b = (bf16*)alloc(4194304L * 2);     // (B,T,16,64)
  bf16* k_r_b = (bf16*)alloc(262144L * 2);      // (B,T,64)
  bf16* vT_b = (bf16*)alloc(8388608L * 2);      // (B,NH,128,T)
  bf16* WuqT_b = Wcat2;
  bf16* Wuk_b = Wcat2 + 1048576L;

  // casts / transposes
  cast_bf16_kernel<<<8192, 256, 0, stream>>>(x, xb, 2097152);
  cast_bf16_kernel<<<1024, 256, 0, stream>>>(W_dq, Wcat, 262144);
  cast_bf16_kernel<<<1024, 256, 0, stream>>>(W_dkv, Wcat + 512L * 2048, 262144);
  cast_bf16_kernel<<<128, 256, 0, stream>>>(W_kr, Wcat + 1024L * 2048, 32768);
  cast_bf16_kernel<<<512, 256, 0, stream>>>(W_qr, Wqr_b, 131072);
  cast_bf16_kernel<<<4096, 256, 0, stream>>>(W_o, Wo_b, 1048576);
  cast_bf16_kernel<<<1024, 256, 0, stream>>>(W_uk, Wuk_b, 262144);
  transpose_cast_kernel<<<dim3(64, 16), dim3(32, 8), 0, stream>>>(W_uq, WuqT_b, 512, 2048);
  transpose_cast_kernel<<<dim3(16, 64), dim3(32, 8), 0, stream>>>(W_uv, WuvT_b, 2048, 512);
  hipMemsetAsync(veff_f32, 0, 1048576L * 4, stream);

  // fused c_q|c_kv|c_kr = x @ Wcat^T : (4096,1088,2048)
  gemm_nt<1><<<dim3(32, 9, 1), 256, 0, stream>>>(xb, Wcat, ckv_all, 4096, 1088, 2048, 2048, 2048,
                                                 1088, 1, 1, 0, 1, 1, 0, 0);
  // veffT = W_o @ W_uv (split-K x4, f32 atomic)
  gemm_nt<2><<<dim3(16, 4, 4), 256, 0, stream>>>(Wo_b, WuvT_b, veff_f32, 2048, 512, 512, 2048,
                                                 2048, 512, 1, 4, 512, 1, 4, 512, 0);
  cast_bf16_kernel<<<1024, 256, 0, stream>>>(veff_f32, veffT_b, 262144);
  // q_h = c_q @ WuqT^T  and  k_h = c_kv @ Wuk^T in one z=2 launch
  gemm_nt<1><<<dim3(32, 16, 2), 256, 0, stream>>>(ckv_all, Wcat2, q_h, 4096, 2048, 512, 1088,
                                                  512, 2048, 1, 2, 512, 1, 2, 1048576, 8388608);
  // c_qr = c_q @ W_qr^T (f32 out)
  gemm_nt<0><<<dim3(32, 8, 1), 256, 0, stream>>>(ckv_all, Wqr_b, c_qr_f, 4096, 1024, 512, 1088,
                                                 512, 1024, 1, 1, 0, 1, 1, 0, 0);
  // vT[b,h](d,s) = veffT_h @ c_kv[b]^T
  gemm_nt<1><<<dim3(1, 8, 64), 256, 0, stream>>>(veffT_b, ckv_all + 512, vT_b, 128, 1024, 512,
                                                 512, 1088, 1024, 1, 16, 65536, 16, 4,
                                                 1024L * 1088, 131072);
  // rope
  rope_q_kernel<<<8192, 256, 0, stream>>>(c_qr_f, fcos, fsin, q_r_b, 2097152);
  rope_k_kernel<<<512, 256, 0, stream>>>(ckv_all, fcos, fsin, k_r_b, 131072);
  // attention
  attn_kernel<<<dim3(4, 16, 4), 512, 0, stream>>>(q_h, q_r_b, k_h, k_r_b, vT_b, out);
}